// Round 2
// baseline (4599.987 us; speedup 1.0000x reference)
//
#include <hip/hip_runtime.h>
#include <hip/hip_bf16.h>
#include <stdint.h>

#define GG 256  // grid extent per axis

// ---------------- rulebook construction ----------------

__global__ __launch_bounds__(256) void k_clear_grid(uint32_t* g, int n32) {
  int i = blockIdx.x * 256 + threadIdx.x;
  int stride = gridDim.x * 256;
  for (; i < n32; i += stride) g[i] = 0xFFFFFFFFu;
}

__global__ __launch_bounds__(256) void k_scatter(const int* __restrict__ coords,
                                                 uint16_t* __restrict__ grid, int n) {
  int i = blockIdx.x * 256 + threadIdx.x;
  if (i >= n) return;
  int x = coords[3 * i], y = coords[3 * i + 1], z = coords[3 * i + 2];
  grid[(((x << 8) | y) << 8) | z] = (uint16_t)i;
}

__global__ __launch_bounds__(256) void k_rulebook(const int* __restrict__ coords,
                                                  const uint16_t* __restrict__ grid,
                                                  int* __restrict__ nidx, int n) {
  int i = blockIdx.x * 256 + threadIdx.x;
  if (i >= n) return;
  int x = coords[3 * i], y = coords[3 * i + 1], z = coords[3 * i + 2];
  int k = 0;
  for (int dx = -1; dx <= 1; ++dx)
    for (int dy = -1; dy <= 1; ++dy)
      for (int dz = -1; dz <= 1; ++dz) {
        int nx = x + dx, ny = y + dy, nz = z + dz;
        int v = -1;
        if (((nx | ny | nz) >= 0) && nx < GG && ny < GG && nz < GG) {
          uint16_t s = grid[(((nx << 8) | ny) << 8) | nz];
          if (s != 0xFFFFu) v = (int)s;
        }
        nidx[k * n + i] = v;  // coalesced across i for each k
        ++k;
      }
}

// ---------------- sparse conv: gather-GEMM (f32 baseline) ----------------
// Block: 64 voxels, 256 threads = 4 waves. Wave w computes Cout quarter w.
// Lane l = voxel within block. Gathered rows staged in LDS (padded +1).

template <int CIN, int COUT>
__global__ __launch_bounds__(256) void k_sconv(const float* __restrict__ feat,
                                               const float* __restrict__ W,
                                               const int* __restrict__ nidx,
                                               float* __restrict__ out, int n) {
  constexpr int BN_ = 64;
  constexpr int DPT = COUT / 4;  // channels per thread
  __shared__ float fs[BN_][CIN + 1];
  __shared__ int nid_s[27][BN_];

  const int bvox = blockIdx.x * BN_;
  const int wave = threadIdx.x >> 6;
  const int lane = threadIdx.x & 63;

  // stage all 27 neighbor ids for this block's voxels
  for (int idx = threadIdx.x; idx < 27 * BN_; idx += 256) {
    int k = idx / BN_, r = idx % BN_;
    int v = bvox + r;
    nid_s[k][r] = (v < n) ? nidx[k * n + v] : -1;
  }

  float acc[DPT];
#pragma unroll
  for (int d = 0; d < DPT; ++d) acc[d] = 0.0f;

  for (int k = 0; k < 27; ++k) {
    __syncthreads();  // covers nid_s (k==0) and prior-iter fs reads
    // gather 64 rows x CIN into LDS (zeros for invalid)
    for (int idx = threadIdx.x; idx < BN_ * CIN; idx += 256) {
      int r = idx / CIN, c = idx % CIN;
      int src = nid_s[k][r];
      fs[r][c] = (src >= 0) ? feat[(size_t)src * CIN + c] : 0.0f;
    }
    __syncthreads();
    const float* Wk = W + k * CIN * COUT;
#pragma unroll 4
    for (int c = 0; c < CIN; ++c) {
      float a = fs[lane][c];
      const float* wrow = Wk + c * COUT + wave * DPT;
#pragma unroll
      for (int d = 0; d < DPT; ++d) acc[d] = fmaf(a, wrow[d], acc[d]);
    }
  }

  int v = bvox + lane;
  if (v < n) {
    float* o = out + (size_t)v * COUT + wave * DPT;
#pragma unroll
    for (int d = 0; d < DPT; ++d) o[d] = acc[d];
  }
}

// ---------------- BN stats (mean, rstd per channel) ----------------

__global__ __launch_bounds__(256) void k_bn_stats(const float* __restrict__ y,
                                                  float* __restrict__ stats, int n, int co) {
  int d = blockIdx.x;
  float s = 0.0f, sq = 0.0f;
  for (int i = threadIdx.x; i < n; i += 256) {
    float v = y[(size_t)i * co + d];
    s += v;
    sq += v * v;
  }
  for (int off = 32; off; off >>= 1) {
    s += __shfl_down(s, off);
    sq += __shfl_down(sq, off);
  }
  __shared__ float ls[4], lq[4];
  int w = threadIdx.x >> 6, l = threadIdx.x & 63;
  if (l == 0) { ls[w] = s; lq[w] = sq; }
  __syncthreads();
  if (threadIdx.x == 0) {
    float S = 0.0f, Q = 0.0f;
    for (int i = 0; i < 4; ++i) { S += ls[i]; Q += lq[i]; }
    float m = S / n;
    float var = Q / n - m * m;
    stats[2 * d] = m;
    stats[2 * d + 1] = rsqrtf(var + 1e-3f);
  }
}

// ---------------- BN apply + ReLU ----------------

__global__ __launch_bounds__(256) void k_bn_relu(const float* __restrict__ y,
                                                 const float* __restrict__ stats,
                                                 const float* __restrict__ g,
                                                 const float* __restrict__ b,
                                                 float* __restrict__ out, int total, int co) {
  int idx = blockIdx.x * 256 + threadIdx.x;
  if (idx >= total) return;
  int d = idx & (co - 1);  // co is a power of two
  float m = stats[2 * d], r = stats[2 * d + 1];
  float v = (y[idx] - m) * r * g[d] + b[d];
  out[idx] = v > 0.0f ? v : 0.0f;
}

// ---------------- host ----------------

struct LayerCfg { int ci, co; };
static const LayerCfg LC[13] = {{4, 16},  {16, 16}, {16, 32}, {32, 32}, {32, 32},
                                {32, 64}, {64, 64}, {64, 64}, {64, 64}, {64, 64},
                                {64, 64}, {64, 64}, {64, 128}};

extern "C" void kernel_launch(void* const* d_in, const int* in_sizes, int n_in,
                              void* d_out, int out_size, void* d_ws, size_t ws_size,
                              hipStream_t stream) {
  const float* vf = (const float*)d_in[0];
  const int* coords = (const int*)d_in[1];
  const int n = in_sizes[1] / 3;

  char* ws = (char*)d_ws;
  size_t off = 0;
  uint16_t* grid = (uint16_t*)(ws + off);
  off += (size_t)GG * GG * GG * 2;           // 33.55 MB
  int* nidx = (int*)(ws + off);
  off += (size_t)27 * n * 4;
  off = (off + 255) & ~(size_t)255;
  float* bufA = (float*)(ws + off);
  off += (size_t)n * 128 * 4;
  off = (off + 255) & ~(size_t)255;
  float* bufB = (float*)(ws + off);
  off += (size_t)n * 128 * 4;
  off = (off + 255) & ~(size_t)255;
  float* stats = (float*)(ws + off);

  const int n32 = GG * GG * GG / 2;
  k_clear_grid<<<2048, 256, 0, stream>>>((uint32_t*)grid, n32);
  k_scatter<<<(n + 255) / 256, 256, 0, stream>>>(coords, grid, n);
  k_rulebook<<<(n + 255) / 256, 256, 0, stream>>>(coords, grid, nidx, n);

  const float* cur = vf;
  for (int L = 0; L < 13; ++L) {
    const float* W = (const float*)d_in[2 + 3 * L];
    const float* g = (const float*)d_in[3 + 3 * L];
    const float* b = (const float*)d_in[4 + 3 * L];
    const int ci = LC[L].ci, co = LC[L].co;
    float* y = bufB;
    const int blocks = (n + 63) / 64;

#define SC(CI, CO) k_sconv<CI, CO><<<blocks, 256, 0, stream>>>(cur, W, nidx, y, n)
    if (ci == 4 && co == 16) SC(4, 16);
    else if (ci == 16 && co == 16) SC(16, 16);
    else if (ci == 16 && co == 32) SC(16, 32);
    else if (ci == 32 && co == 32) SC(32, 32);
    else if (ci == 32 && co == 64) SC(32, 64);
    else if (ci == 64 && co == 64) SC(64, 64);
    else SC(64, 128);
#undef SC

    k_bn_stats<<<co, 256, 0, stream>>>(y, stats, n, co);

    float* dst = (L == 12) ? (float*)d_out : bufA;
    const int total = n * co;
    k_bn_relu<<<(total + 255) / 256, 256, 0, stream>>>(y, stats, g, b, dst, total, co);
    cur = dst;
  }
}

// Round 3
// 648.127 us; speedup vs baseline: 7.0974x; 7.0974x over previous
//
#include <hip/hip_runtime.h>
#include <stdint.h>
#include <stddef.h>

#define GG 256  // voxel grid extent per axis

typedef __attribute__((ext_vector_type(8))) short bf16x8;
typedef __attribute__((ext_vector_type(4))) float f32x4;

__device__ __forceinline__ float bf2f(short s) {
  return __builtin_bit_cast(float, ((unsigned)(unsigned short)s) << 16);
}
__device__ __forceinline__ short f2bf(float f) {
  unsigned u = __builtin_bit_cast(unsigned, f);
  unsigned r = (u + 0x7FFFu + ((u >> 16) & 1u)) >> 16;
  return (short)r;
}

// ---------------- rulebook construction ----------------

__global__ __launch_bounds__(256) void k_clear_grid(uint32_t* g, int n32) {
  int i = blockIdx.x * 256 + threadIdx.x;
  int stride = gridDim.x * 256;
  for (; i < n32; i += stride) g[i] = 0xFFFFFFFFu;
}

__global__ __launch_bounds__(256) void k_scatter(const int* __restrict__ coords,
                                                 uint16_t* __restrict__ grid, int n) {
  int i = blockIdx.x * 256 + threadIdx.x;
  if (i >= n) return;
  int x = coords[3 * i], y = coords[3 * i + 1], z = coords[3 * i + 2];
  grid[(((x << 8) | y) << 8) | z] = (uint16_t)i;
}

__global__ __launch_bounds__(256) void k_rulebook(const int* __restrict__ coords,
                                                  const uint16_t* __restrict__ grid,
                                                  int* __restrict__ nidx, int n) {
  int i = blockIdx.x * 256 + threadIdx.x;
  if (i >= n) return;
  int x = coords[3 * i], y = coords[3 * i + 1], z = coords[3 * i + 2];
  int k = 0;
  for (int dx = -1; dx <= 1; ++dx)
    for (int dy = -1; dy <= 1; ++dy)
      for (int dz = -1; dz <= 1; ++dz) {
        int nx = x + dx, ny = y + dy, nz = z + dz;
        int v = -1;
        if (((nx | ny | nz) >= 0) && nx < GG && ny < GG && nz < GG) {
          uint16_t s = grid[(((nx << 8) | ny) << 8) | nz];
          if (s != 0xFFFFu) v = (int)s;
        }
        nidx[k * n + i] = v;
        ++k;
      }
}

// ---------------- misc zero (stats + zero-page) ----------------

__global__ __launch_bounds__(256) void k_zero(float* __restrict__ stats, float* __restrict__ zp) {
  int i = blockIdx.x * 256 + threadIdx.x;
  if (i < 13 * 256) stats[i] = 0.0f;
  if (i < 64) zp[i] = 0.0f;
}

// ---------------- weight pack: W[27][ci][co] f32 -> P[kb][co][32] bf16 ----------------

struct PackArgs {
  const float* W[13];
  short* P[13];
  int ci[13], co[13], nkb[13];
};

__global__ __launch_bounds__(256) void k_pack(PackArgs pa) {
  int L = blockIdx.y;
  int ci = pa.ci[L], co = pa.co[L], nkb = pa.nkb[L];
  int total = nkb * co * 32;
  const float* W = pa.W[L];
  short* P = pa.P[L];
  for (int e = blockIdx.x * 256 + threadIdx.x; e < total; e += gridDim.x * 256) {
    int kk = e & 31;
    int rest = e >> 5;
    int c = rest % co;
    int kb = rest / co;
    int k = kb * 32 + kk;
    int tap = k / ci, cc = k % ci;
    float v = (tap < 27) ? W[((size_t)tap * ci + cc) * co + c] : 0.0f;
    P[e] = f2bf(v);
  }
}

// ---------------- layer 0 (Ci=4 -> Co=16), f32 VALU, one thread per voxel ----------------

__global__ __launch_bounds__(256) void k_sconv_l0(const float* __restrict__ feat,
                                                  const float* __restrict__ W,  // [27][4][16]
                                                  const int* __restrict__ nidx,
                                                  float* __restrict__ y,
                                                  float* __restrict__ stats, int n) {
  int i = blockIdx.x * 256 + threadIdx.x;
  bool act = i < n;
  int ii = act ? i : (n - 1);
  float acc[16];
#pragma unroll
  for (int c = 0; c < 16; ++c) acc[c] = 0.0f;
  for (int t = 0; t < 27; ++t) {
    int nid = nidx[t * n + ii];
    float4 f = make_float4(0.f, 0.f, 0.f, 0.f);
    if (act && nid >= 0) f = *(const float4*)(feat + 4 * (size_t)nid);
    const float* Wt = W + t * 64;
#pragma unroll
    for (int c = 0; c < 16; ++c)
      acc[c] = fmaf(f.x, Wt[c],
               fmaf(f.y, Wt[16 + c],
               fmaf(f.z, Wt[32 + c],
               fmaf(f.w, Wt[48 + c], acc[c]))));
  }
  if (act) {
    float* o = y + (size_t)i * 16;
#pragma unroll
    for (int c = 0; c < 16; c += 4) *(float4*)(o + c) = make_float4(acc[c], acc[c+1], acc[c+2], acc[c+3]);
  }
  // fused BN sums
  __shared__ float ss[4][16], sq[4][16];
  int w = threadIdx.x >> 6, l = threadIdx.x & 63;
#pragma unroll
  for (int c = 0; c < 16; ++c) {
    float s = act ? acc[c] : 0.0f;
    float q = s * s;
#pragma unroll
    for (int off = 32; off; off >>= 1) {
      s += __shfl_xor(s, off);
      q += __shfl_xor(q, off);
    }
    if (l == 0) { ss[w][c] = s; sq[w][c] = q; }
  }
  __syncthreads();
  if (threadIdx.x < 16) {
    int c = threadIdx.x;
    atomicAdd(&stats[c], ss[0][c] + ss[1][c] + ss[2][c] + ss[3][c]);
    atomicAdd(&stats[16 + c], sq[0][c] + sq[1][c] + sq[2][c] + sq[3][c]);
  }
}

// ---------------- MFMA sparse conv (Ci in {16,32,64}) ----------------
// Block: 64 voxel rows, 4 waves. Wave w owns m-tile w (16 rows), iterates all
// Co/16 n-tiles. A-fragments gathered per-lane directly from global (L2);
// invalid neighbors read a zeroed page. B from packed P[kb][co][32].
// mfma_f32_16x16x32_bf16: A: lane holds A[row=l&15][k=8*(l>>4)+b];
//                         B: lane holds B[k=8*(l>>4)+b][col=l&15];
//                         C/D: col=l&15, row=4*(l>>4)+r (m89-verified).

template <int CI, int CO>
__global__ __launch_bounds__(256) void k_sconv_mfma(
    const short* __restrict__ feat, const short* __restrict__ P,
    const int* __restrict__ nidx, const short* __restrict__ zpage,
    short* __restrict__ y, float* __restrict__ stats, int n) {
  constexpr int LOG2CI = (CI == 16) ? 4 : (CI == 32) ? 5 : 6;
  constexpr int NKB = (27 * CI + 31) / 32;  // K-steps of 32
  constexpr int NT = CO / 16;               // n-tiles per wave

  const int w = threadIdx.x >> 6;
  const int l = threadIdx.x & 63;
  const int lo = l & 15, g = l >> 4;
  const int bvox = blockIdx.x * 64;
  const int rowg = bvox + 16 * w + lo;
  const int rowc = (rowg < n) ? rowg : (n - 1);

  f32x4 acc[NT];
#pragma unroll
  for (int t = 0; t < NT; ++t) acc[t] = (f32x4){0.f, 0.f, 0.f, 0.f};

  auto loadA = [&](int kb) -> bf16x8 {
    int kg = kb * 32 + 8 * g;
    int tap = kg >> LOG2CI;
    int ch = kg & (CI - 1);
    const short* ap = zpage;
    if (tap < 27) {
      int nid = nidx[tap * n + rowc];
      if (nid >= 0) ap = feat + (size_t)nid * CI + ch;
    }
    return *(const bf16x8*)ap;
  };
  auto loadB = [&](int kb, int t) -> bf16x8 {
    return *(const bf16x8*)(P + ((size_t)(kb * CO + 16 * t + lo)) * 32 + 8 * g);
  };

  bf16x8 a = loadA(0);
  bf16x8 b[NT];
#pragma unroll
  for (int t = 0; t < NT; ++t) b[t] = loadB(0, t);

  for (int kb = 0; kb < NKB - 1; ++kb) {
    bf16x8 an = loadA(kb + 1);
    bf16x8 bn[NT];
#pragma unroll
    for (int t = 0; t < NT; ++t) bn[t] = loadB(kb + 1, t);
#pragma unroll
    for (int t = 0; t < NT; ++t)
      acc[t] = __builtin_amdgcn_mfma_f32_16x16x32_bf16(a, b[t], acc[t], 0, 0, 0);
    a = an;
#pragma unroll
    for (int t = 0; t < NT; ++t) b[t] = bn[t];
  }
#pragma unroll
  for (int t = 0; t < NT; ++t)
    acc[t] = __builtin_amdgcn_mfma_f32_16x16x32_bf16(a, b[t], acc[t], 0, 0, 0);

  // epilogue: write y (bf16) + fused BN sums
  __shared__ float ss[4][CO], sq[4][CO];
#pragma unroll
  for (int t = 0; t < NT; ++t) {
    int col = 16 * t + lo;
    float sv = 0.f, qv = 0.f;
#pragma unroll
    for (int r = 0; r < 4; ++r) {
      int row = bvox + 16 * w + 4 * g + r;
      float v = acc[t][r];
      bool valid = row < n;
      if (valid) y[(size_t)row * CO + col] = f2bf(v);
      v = valid ? v : 0.f;
      sv += v;
      qv += v * v;
    }
    sv += __shfl_xor(sv, 16); sv += __shfl_xor(sv, 32);
    qv += __shfl_xor(qv, 16); qv += __shfl_xor(qv, 32);
    if (g == 0) { ss[w][col] = sv; sq[w][col] = qv; }
  }
  __syncthreads();
  for (int c = threadIdx.x; c < CO; c += 256) {
    atomicAdd(&stats[c], ss[0][c] + ss[1][c] + ss[2][c] + ss[3][c]);
    atomicAdd(&stats[CO + c], sq[0][c] + sq[1][c] + sq[2][c] + sq[3][c]);
  }
}

// ---------------- BN apply + ReLU (+dtype conversion) ----------------

template <int CO, bool INF32, bool OUTF32>
__global__ __launch_bounds__(256) void k_bn_apply(const void* __restrict__ yv,
                                                  const float* __restrict__ stats,
                                                  const float* __restrict__ gam,
                                                  const float* __restrict__ bet,
                                                  void* __restrict__ outv, int n) {
  int idx = blockIdx.x * 256 + threadIdx.x;
  int tot = n * CO / 8;
  if (idx >= tot) return;
  size_t e0 = (size_t)idx * 8;
  int c0 = (int)(e0 & (CO - 1));
  float invn = 1.0f / (float)n;

  float vin[8];
  if (INF32) {
    const float4* p = (const float4*)((const float*)yv + e0);
    float4 u0 = p[0], u1 = p[1];
    vin[0] = u0.x; vin[1] = u0.y; vin[2] = u0.z; vin[3] = u0.w;
    vin[4] = u1.x; vin[5] = u1.y; vin[6] = u1.z; vin[7] = u1.w;
  } else {
    bf16x8 v = *(const bf16x8*)((const short*)yv + e0);
#pragma unroll
    for (int j = 0; j < 8; ++j) vin[j] = bf2f(v[j]);
  }

  float vout[8];
#pragma unroll
  for (int j = 0; j < 8; ++j) {
    int c = c0 + j;
    float m = stats[c] * invn;
    float var = fmaf(-m, m, stats[CO + c] * invn);
    float rstd = rsqrtf(var + 1e-3f);
    float o = fmaf((vin[j] - m) * rstd, gam[c], bet[c]);
    vout[j] = fmaxf(o, 0.0f);
  }

  if (OUTF32) {
    float4* p = (float4*)((float*)outv + e0);
    p[0] = make_float4(vout[0], vout[1], vout[2], vout[3]);
    p[1] = make_float4(vout[4], vout[5], vout[6], vout[7]);
  } else {
    bf16x8 o;
#pragma unroll
    for (int j = 0; j < 8; ++j) o[j] = f2bf(vout[j]);
    *(bf16x8*)((short*)outv + e0) = o;
  }
}

// ---------------- host ----------------

extern "C" void kernel_launch(void* const* d_in, const int* in_sizes, int n_in,
                              void* d_out, int out_size, void* d_ws, size_t ws_size,
                              hipStream_t stream) {
  const float* vf = (const float*)d_in[0];
  const int* coords = (const int*)d_in[1];
  const int n = in_sizes[1] / 3;

  static const int CIs[13] = {4, 16, 16, 32, 32, 32, 64, 64, 64, 64, 64, 64, 64};
  static const int COs[13] = {16, 16, 32, 32, 32, 64, 64, 64, 64, 64, 64, 64, 128};

  char* ws = (char*)d_ws;
  size_t off = 0;
  auto carve = [&](size_t bytes) { void* p = ws + off; off = (off + bytes + 255) & ~(size_t)255; return p; };
  uint16_t* grid = (uint16_t*)carve((size_t)GG * GG * GG * 2);
  int* nidx = (int*)carve((size_t)27 * n * 4);
  short* featA = (short*)carve((size_t)n * 128 * 2);
  short* featB = (short*)carve((size_t)n * 128 * 2);
  short* y = (short*)carve((size_t)n * 128 * 2);
  short* Ppool = (short*)carve((size_t)2 * 1024 * 1024 * 2);  // 4MB pool, ~2.05MB used
  float* stats = (float*)carve((size_t)13 * 256 * 4);
  float* zpage = (float*)carve(256);

  // per-layer packed-weight pointers
  PackArgs pa;
  {
    size_t poff = 0;
    for (int L = 0; L < 13; ++L) {
      int ci = CIs[L], co = COs[L];
      int nkb = (27 * ci + 31) / 32;
      pa.W[L] = (const float*)d_in[2 + 3 * L];
      pa.P[L] = Ppool + poff;
      pa.ci[L] = ci; pa.co[L] = co; pa.nkb[L] = nkb;
      poff += (size_t)nkb * co * 32;
    }
  }

  const int n32 = GG * GG * GG / 2;
  k_clear_grid<<<2048, 256, 0, stream>>>((uint32_t*)grid, n32);
  k_scatter<<<(n + 255) / 256, 256, 0, stream>>>(coords, grid, n);
  k_rulebook<<<(n + 255) / 256, 256, 0, stream>>>(coords, grid, nidx, n);
  k_zero<<<13, 256, 0, stream>>>(stats, zpage);
  k_pack<<<dim3(128, 13), 256, 0, stream>>>(pa);

  // ---- layer 0 (f32 path) ----
  k_sconv_l0<<<(n + 255) / 256, 256, 0, stream>>>(vf, pa.W[0], nidx, (float*)y, stats, n);
  k_bn_apply<16, true, false><<<((n * 16 / 8) + 255) / 256, 256, 0, stream>>>(
      (const void*)y, stats, (const float*)d_in[3], (const float*)d_in[4], (void*)featA, n);

  // ---- layers 1..12 (MFMA path) ----
  short* cur = featA;
  short* nxt = featB;
  const int nb64 = (n + 63) / 64;

#define RUN_MFMA(L, CI, CO, LAST)                                                             \
  do {                                                                                        \
    float* st = stats + 256 * (L);                                                            \
    k_sconv_mfma<CI, CO><<<nb64, 256, 0, stream>>>(cur, (const short*)pa.P[L], nidx,          \
                                                   (const short*)zpage, y, st, n);            \
    const float* gg = (const float*)d_in[3 + 3 * (L)];                                        \
    const float* bb = (const float*)d_in[4 + 3 * (L)];                                        \
    int nb = ((n * (CO) / 8) + 255) / 256;                                                    \
    if (LAST) {                                                                               \
      k_bn_apply<CO, false, true><<<nb, 256, 0, stream>>>((const void*)y, st, gg, bb,         \
                                                          (void*)d_out, n);                   \
    } else {                                                                                  \
      k_bn_apply<CO, false, false><<<nb, 256, 0, stream>>>((const void*)y, st, gg, bb,        \
                                                           (void*)nxt, n);                    \
      short* t_ = cur; cur = nxt; nxt = t_;                                                   \
    }                                                                                         \
  } while (0)

  RUN_MFMA(1, 16, 16, false);
  RUN_MFMA(2, 16, 32, false);
  RUN_MFMA(3, 32, 32, false);
  RUN_MFMA(4, 32, 32, false);
  RUN_MFMA(5, 32, 64, false);
  RUN_MFMA(6, 64, 64, false);
  RUN_MFMA(7, 64, 64, false);
  RUN_MFMA(8, 64, 64, false);
  RUN_MFMA(9, 64, 64, false);
  RUN_MFMA(10, 64, 64, false);
  RUN_MFMA(11, 64, 64, false);
  RUN_MFMA(12, 64, 128, true);
#undef RUN_MFMA
}